// Round 16
// baseline (95.314 us; speedup 1.0000x reference)
//
#include <hip/hip_runtime.h>
#include <hip/hip_bf16.h>
#include <hip/hip_cooperative_groups.h>

namespace cg = cooperative_groups;

// LearnableInterpolation: out[b,t,n] = sum_o softmax_o(-3*(tpos[o,n]-tgt[t])^2) * x[b,o,n]
// B=32, L_org=L_to=2048, N=21. Softmax over o is a near-delta -> 9-tap window.
//
// R16: the fused-gather family is pinned at ~16.3us by the scattered-access
// latency stream (4.1M line-grain transactions; occupancy/request/store
// levers all null, R9/R11/R14/R15). The only structural fix is reading from
// a transposed copy, and a second dispatch costs +5us (proven 3x). So:
// ONE cooperative kernel with a grid-wide sync:
//   phase A: tiled transpose x -> xt[N,B,L] in d_ws (coalesced both sides)
//   grid.sync()
//   phase B: block=(b, 64-t-tile); wave handles ~5 channels; per (n,lane):
//     R15-verbatim 9-tap weights, then 9 scalar loads row[o0+j] whose
//     lane-consecutive addresses hardware-coalesce and stay L1-resident
//     (each line reused 9x). No LDS, no block barrier. Scattered stores
//     (proven free; R7: never NT them).
// Fallback (ws too small / coop launch rejected): R15 kernel at 16.2us.

constexpr int LORG  = 2048;
constexpr int LTO   = 2048;
constexpr int NCH   = 21;
constexpr int BATCH = 32;
constexpr int W     = 4;
constexpr int NW    = 2 * W + 1;    // 9 taps
constexpr int NBLK  = BATCH * 32;   // 1024 blocks: (b, 64-wide t-tile)

constexpr float MIN_RATIO = 0.7f, MAX_RATIO = 1.3f;
constexpr float MIN_BIAS  = -4.0f, MAX_BIAS = 4.0f;
constexpr float NEG3LOG2E = -3.0f * 1.4426950408889634f;  // log2-domain scale

__device__ __forceinline__ int compute_o0(float tg, float bb, float ir) {
    const float ocf = (float)LORG + (tg - bb) * ir;
    int o0 = (int)floorf(ocf + 0.5f) - W;
    return max(0, min(LORG - NW, o0));
}

// ---------------- cooperative kernel: transpose + sync + interp -------------
__global__ __launch_bounds__(256) void li_coop(
    const float* __restrict__ x,      // [B, LORG, NCH]
    const float* __restrict__ rmo,    // [NCH]
    const float* __restrict__ bias,   // [NCH]
    float* __restrict__ out,          // [B, LTO, NCH]
    float* __restrict__ xt)           // [NCH, BATCH, LORG] workspace
{
    const int h   = blockIdx.x;
    const int b   = h >> 5;                // 0..31
    const int q   = h & 31;                // chunk / t-tile index 0..31
    const int tid = threadIdx.x;

    // ---- phase A: transpose 64 rows x[b, q*64.., :21] -> xt ----
    __shared__ float tile[64 * NCH];
    {
        const float4* src = (const float4*)(x + ((size_t)b * LORG + q * 64) * NCH);
        float4* t4 = (float4*)tile;
        #pragma unroll
        for (int i = tid; i < 64 * NCH / 4; i += 256) t4[i] = src[i];
        __syncthreads();
        for (int j = tid; j < 64 * NCH; j += 256) {
            const int n = j >> 6, k = j & 63;      // lane==k -> coalesced write
            xt[((size_t)n * BATCH + b) * LORG + q * 64 + k] = tile[k * NCH + n];
        }
    }

    cg::this_grid().sync();

    // ---- phase B: interp for (b, t0..t0+63), all 21 channels ----
    const int t0   = q * 64;
    const int lane = tid & 63;
    const int wv   = tid >> 6;
    const float tg = (float)(t0 + lane - LTO);

    for (int n = wv; n < NCH; n += 4) {
        const float r  = fminf(fmaxf(rmo[n] + 1.0f, MIN_RATIO), MAX_RATIO);
        const float bb = fminf(fmaxf(bias[n], MIN_BIAS), MAX_BIAS);
        const float ir = 1.0f / r;
        const int   o0 = compute_o0(tg, bb, ir);

        float d = (float)(o0 - LORG) * r + bb - tg;   // d_j = d + j*r
        // analytic max of -3*d_j^2 over j in [0,8] (LOAD-BEARING in clamp
        // regions where |d|~200: without it all exp2 flush to 0 -> NaN)
        float js = floorf(-d * ir + 0.5f);
        js = fminf(fmaxf(js, 0.0f), 8.0f);
        const float ds = d + js * r;
        const float m  = NEG3LOG2E * ds * ds;         // log2-domain max
        float w[NW];
        float sum = 0.0f;
        #pragma unroll
        for (int j = 0; j < NW; ++j) {
            w[j] = exp2f(NEG3LOG2E * d * d - m);      // native v_exp_f32
            sum += w[j];
            d += r;
        }
        const float inv = 1.0f / sum;                 // sum >= 1, no NaN

        // 9 scalar loads, lane-consecutive addresses -> HW-coalesced, L1-hot
        const float* row = xt + ((size_t)n * BATCH + b) * LORG;
        float acc = 0.0f;
        #pragma unroll
        for (int j = 0; j < NW; ++j)
            acc = fmaf(w[j], row[o0 + j], acc);
        out[((size_t)b * LTO + t0 + lane) * NCH + n] = acc * inv;
    }
}

// ---------------- fallback: R15 fused kernel (16.2us, proven) ---------------
constexpr int FTT   = 128;
constexpr int FBH   = 4;
constexpr int FXCAP = 200;
constexpr int FNBLK = (LTO / FTT) * NCH * (BATCH / FBH);   // 2688

__global__ __launch_bounds__(256) void li_fused(
    const float* __restrict__ x,
    const float* __restrict__ rmo,
    const float* __restrict__ bias,
    float* __restrict__ out)
{
    const int h    = blockIdx.x;
    const int wk   = (h & 7) * (FNBLK / 8) + (h >> 3);
    const int bg   = wk & 7;
    const int rest = wk >> 3;
    const int n    = rest % NCH;
    const int tt   = rest / NCH;
    const int t0   = tt * FTT;
    const int b0   = bg * FBH;

    const int tid  = threadIdx.x;
    const int lane = tid & 63;
    const int wv   = tid >> 6;

    __shared__ float xs[FBH][FXCAP];

    const float r  = fminf(fmaxf(rmo[n] + 1.0f, MIN_RATIO), MAX_RATIO);
    const float bb = fminf(fmaxf(bias[n], MIN_BIAS), MAX_BIAS);
    const float ir = 1.0f / r;

    const int lo  = compute_o0((float)(t0 - LTO), bb, ir);
    const int hi  = compute_o0((float)(t0 + FTT - 1 - LTO), bb, ir);
    const int len = hi + NW - lo;

    const int b = b0 + wv;
    {
        const float* col = x + ((size_t)(b * LORG + lo)) * NCH + n;
        for (int i = lane; i < len; i += 64)
            xs[wv][i] = col[(size_t)i * NCH];
    }

    #pragma unroll
    for (int half = 0; half < 2; ++half) {
        const int   tl = lane + 64 * half;
        const float tg = (float)(t0 + tl - LTO);
        const int   o0 = compute_o0(tg, bb, ir);
        const int base = o0 - lo;
        float d = (float)(o0 - LORG) * r + bb - tg;
        float js = floorf(-d * ir + 0.5f);
        js = fminf(fmaxf(js, 0.0f), 8.0f);
        const float ds = d + js * r;
        const float m  = NEG3LOG2E * ds * ds;
        float w[NW];
        float sum = 0.0f;
        #pragma unroll
        for (int j = 0; j < NW; ++j) {
            w[j] = exp2f(NEG3LOG2E * d * d - m);
            sum += w[j];
            d += r;
        }
        const float inv = 1.0f / sum;

        float acc = 0.0f;
        #pragma unroll
        for (int j = 0; j < NW; ++j)
            acc = fmaf(w[j], xs[wv][base + j], acc);
        out[((size_t)b * LTO + t0 + tl) * NCH + n] = acc * inv;
    }
}

extern "C" void kernel_launch(void* const* d_in, const int* in_sizes, int n_in,
                              void* d_out, int out_size, void* d_ws, size_t ws_size,
                              hipStream_t stream) {
    const float* x    = (const float*)d_in[0];
    const float* rmo  = (const float*)d_in[1];
    const float* bias = (const float*)d_in[2];
    float* out = (float*)d_out;

    const size_t xt_bytes = (size_t)NCH * BATCH * LORG * sizeof(float);
    bool done = false;
    if (ws_size >= xt_bytes) {
        float* xt = (float*)d_ws;
        void* args[] = { (void*)&x, (void*)&rmo, (void*)&bias,
                         (void*)&out, (void*)&xt };
        hipError_t e = hipLaunchCooperativeKernel(
            (const void*)li_coop, dim3(NBLK), dim3(256), args, 0, stream);
        done = (e == hipSuccess);
    }
    if (!done) {
        li_fused<<<FNBLK, 256, 0, stream>>>(x, rmo, bias, out);
    }
}

// Round 17
// 16.085 us; speedup vs baseline: 5.9256x; 5.9256x over previous
//
#include <hip/hip_runtime.h>
#include <hip/hip_bf16.h>

// LearnableInterpolation: out[b,t,n] = sum_o softmax_o(-3*(tpos[o,n]-tgt[t])^2) * x[b,o,n]
// B=32, L_org=L_to=2048, N=21. Softmax over o is a near-delta -> 9-tap window.
//
// R17 == R15 (best measured: 16.22us, passed). Restoring after R16's
// cooperative grid.sync experiment regressed to 95us (grid-wide sync costs
// ~60us on MI355X — never again, like R7's NT scattered stores).
//
// Final structure (fused-gather family):
//  - single kernel; block = (128-t-tile, n, 4 batches); 2688 blocks
//    (10.5/CU -> full 32-wave occupancy);
//  - per-wave barrier-free LDS: wave wv stages its batch's window
//    (len<=192, guarded strided gather) then computes 2 t-halves;
//  - 9-tap window (dropped softmax mass ~2e-13 relative);
//  - log2-domain weights with analytic max-subtract (LOAD-BEARING in
//    o0-clamp regions where |d|~200: all exp2 would flush to 0 -> NaN);
//  - regular scattered stores (L2 write-back coalesces; NT = +10us).
//
// Plateau evidence (16.2-16.9us across 11 variants): occupancy +52% -> +3%
// (R9); store-coalescing null (R11); request-count -17% null (R15); taps
// 17->9 null (R14); pipelining null (R8); transpose two-kernel +5us tax
// (R2/R5/R10); o-chunk coalesced-everything 2.3x slower (R12/R13); coop
// grid-sync 6x slower (R16). Residual is unhidden scattered-access latency
// + dispatch overhead, not any counter-visible throughput limit.

constexpr int LORG  = 2048;
constexpr int LTO   = 2048;
constexpr int NCH   = 21;
constexpr int BATCH = 32;
constexpr int W     = 4;
constexpr int NW    = 2 * W + 1;    // 9 taps
constexpr int TT    = 128;          // t-tile
constexpr int BH    = 4;            // batches per block (1 per wave)
constexpr int XCAP  = 200;          // window cap: ceil(127/0.7)+1+9 = 192
constexpr int NBLK  = (LTO / TT) * NCH * (BATCH / BH);   // 16*21*8 = 2688

constexpr float MIN_RATIO = 0.7f, MAX_RATIO = 1.3f;
constexpr float MIN_BIAS  = -4.0f, MAX_BIAS = 4.0f;
constexpr float NEG3LOG2E = -3.0f * 1.4426950408889634f;  // log2-domain scale

__device__ __forceinline__ int compute_o0(float tg, float bb, float ir) {
    const float ocf = (float)LORG + (tg - bb) * ir;
    int o0 = (int)floorf(ocf + 0.5f) - W;
    return max(0, min(LORG - NW, o0));
}

__global__ __launch_bounds__(256) void li_fused(
    const float* __restrict__ x,      // [B, LORG, NCH]
    const float* __restrict__ rmo,    // [NCH]
    const float* __restrict__ bias,   // [NCH]
    float* __restrict__ out)          // [B, LTO, NCH]
{
    // XCD swizzle: 2688 = 8*336; bg fastest, then n, then t-tile, so blocks
    // sharing x rows (same t-tile) cluster on one XCD's L2.
    const int h    = blockIdx.x;
    const int wk   = (h & 7) * (NBLK / 8) + (h >> 3);
    const int bg   = wk & 7;               // batch group 0..7
    const int rest = wk >> 3;
    const int n    = rest % NCH;
    const int tt   = rest / NCH;           // 0..15
    const int t0   = tt * TT;
    const int b0   = bg * BH;

    const int tid  = threadIdx.x;
    const int lane = tid & 63;
    const int wv   = tid >> 6;             // wave id 0..3 -> its batch

    __shared__ float xs[BH][XCAP];         // 4*200*4B = 3.2 KB

    const float r  = fminf(fmaxf(rmo[n] + 1.0f, MIN_RATIO), MAX_RATIO);
    const float bb = fminf(fmaxf(bias[n], MIN_BIAS), MAX_BIAS);
    const float ir = 1.0f / r;

    // block-wide window (o0 monotone in t)
    const int lo  = compute_o0((float)(t0 - LTO), bb, ir);
    const int hi  = compute_o0((float)(t0 + TT - 1 - LTO), bb, ir);
    const int len = hi + NW - lo;          // <= 192 < XCAP

    // ---- per-wave staging of its batch (barrier-free, guarded) ----
    const int b = b0 + wv;
    {
        const float* col = x + ((size_t)(b * LORG + lo)) * NCH + n;
        for (int i = lane; i < len; i += 64)
            xs[wv][i] = col[(size_t)i * NCH];
    }

    // ---- compute: 2 t-halves sequentially, 1 batch ----
    #pragma unroll
    for (int half = 0; half < 2; ++half) {
        const int   tl = lane + 64 * half;
        const float tg = (float)(t0 + tl - LTO);
        const int   o0 = compute_o0(tg, bb, ir);
        const int base = o0 - lo;
        float d = (float)(o0 - LORG) * r + bb - tg;   // d_j = d + j*r
        // analytic max of -3*d_j^2 over j in [0,8]: nearest j to -d/r
        float js = floorf(-d * ir + 0.5f);
        js = fminf(fmaxf(js, 0.0f), 8.0f);
        const float ds = d + js * r;
        const float m  = NEG3LOG2E * ds * ds;         // log2-domain max
        float w[NW];
        float sum = 0.0f;
        #pragma unroll
        for (int j = 0; j < NW; ++j) {
            w[j] = exp2f(NEG3LOG2E * d * d - m);      // native v_exp_f32
            sum += w[j];
            d += r;
        }
        const float inv = 1.0f / sum;                 // sum >= 1, no NaN

        float acc = 0.0f;
        #pragma unroll
        for (int j = 0; j < NW; ++j)
            acc = fmaf(w[j], xs[wv][base + j], acc);
        out[((size_t)b * LTO + t0 + tl) * NCH + n] = acc * inv;
    }
}

extern "C" void kernel_launch(void* const* d_in, const int* in_sizes, int n_in,
                              void* d_out, int out_size, void* d_ws, size_t ws_size,
                              hipStream_t stream) {
    const float* x    = (const float*)d_in[0];
    const float* rmo  = (const float*)d_in[1];
    const float* bias = (const float*)d_in[2];
    float* out = (float*)d_out;

    li_fused<<<NBLK, 256, 0, stream>>>(x, rmo, bias, out);
}